// Round 1
// baseline (8212.072 us; speedup 1.0000x reference)
//
#include <hip/hip_runtime.h>
#include <math.h>

#define Bb 64
#define Pp 196
#define ENCd 2048
#define Lc 20
#define Tt 19
#define Vv 10000
#define Ee 512
#define Dd 512
#define Aa 512
#define KIH 2560   // E + ENC
#define G4 2048    // 4*D

#define OUT_PRED 0ll
#define OUT_CAPS 12160000ll   // B*T*V
#define OUT_ALPH 12161280ll   // + B*L
#define OUT_SIND 12399616ll   // + B*T*P

// ---------------- sort (stable descending argsort of caption lengths) ---------
__global__ void k_sort(const int* __restrict__ cap_len, const int* __restrict__ caps_in,
                       float* __restrict__ out, int* __restrict__ sind,
                       int* __restrict__ dlen, int* __restrict__ caps_s) {
    __shared__ int cls[Bb];
    int i = threadIdx.x;
    int cl = cap_len[i];           // shape (B,1)
    cls[i] = cl;
    __syncthreads();
    int rank = 0;
    for (int j = 0; j < Bb; ++j) {
        int cj = cls[j];
        rank += (cj > cl) || (cj == cl && j < i);
    }
    sind[rank] = i;
    dlen[rank] = cl - 1;
    out[OUT_SIND + rank] = (float)i;
    for (int l = 0; l < Lc; ++l) {
        int v = caps_in[i * Lc + l];
        caps_s[rank * Lc + l] = v;
        out[OUT_CAPS + rank * Lc + l] = (float)v;
    }
}

// ---------------- mean over pixels ------------------------------------------
__global__ void k_meanenc(const float* __restrict__ enc, const int* __restrict__ sind,
                          float* __restrict__ mean_enc) {
    int id = blockIdx.x * 256 + threadIdx.x;   // 64*2048
    int b = id >> 11, e = id & 2047;
    const float* p = enc + (size_t)sind[b] * Pp * ENCd + e;
    float s = 0.f;
    for (int k = 0; k < Pp; ++k) s += p[(size_t)k * ENCd];
    mean_enc[id] = s * (1.0f / Pp);
}

// ---------------- generic fp32 GEMM: C[M,N] = act(A[M,K] * W[N,K]^T + bias) --
// BM=64, BN=64, BK=16; block 256; 4x4 per thread.
// sindp: optional row gather (att1): physical row = sindp[row/196]*196 + row%196
// partial: write raw partial to C + blockIdx.z*partStride (row*N+n), no bias/act
// dlen/t: optional mask (batch m): write 0 when t >= dlen[m]
__global__ void __launch_bounds__(256) k_gemm(
        const float* __restrict__ A, int lda, const int* __restrict__ sindp,
        const float* __restrict__ W, const float* __restrict__ bias,
        float* __restrict__ C, long long ldc, long long coloff,
        int N, int K, int klen,
        int act, int partial, long long partStride,
        const int* __restrict__ dlen, int t) {
    __shared__ float As[16][68];
    __shared__ float Bs[16][68];
    int tid = threadIdx.x;
    int tx = tid & 15, ty = tid >> 4;
    int m0 = blockIdx.y * 64;
    int n0 = blockIdx.x * 64;
    int k0base = blockIdx.z * klen;
    float acc[4][4] = {};
    int kk = tid & 15;
    for (int k0 = k0base; k0 < k0base + klen; k0 += 16) {
        #pragma unroll
        for (int pass = 0; pass < 4; ++pass) {
            int mm = (tid >> 4) + pass * 16;
            int row = m0 + mm;
            int rphys;
            if (sindp) { int bb = row / Pp; rphys = sindp[bb] * Pp + (row - bb * Pp); }
            else rphys = row;
            As[kk][mm] = A[(size_t)rphys * lda + k0 + kk];
            int col = n0 + mm;
            Bs[kk][mm] = (col < N) ? W[(size_t)col * K + k0 + kk] : 0.0f;
        }
        __syncthreads();
        #pragma unroll
        for (int kk2 = 0; kk2 < 16; ++kk2) {
            float4 a4 = *(const float4*)&As[kk2][ty * 4];
            float4 b4 = *(const float4*)&Bs[kk2][tx * 4];
            float av[4] = {a4.x, a4.y, a4.z, a4.w};
            float bv[4] = {b4.x, b4.y, b4.z, b4.w};
            #pragma unroll
            for (int i = 0; i < 4; ++i)
                #pragma unroll
                for (int j = 0; j < 4; ++j)
                    acc[i][j] += av[i] * bv[j];
        }
        __syncthreads();
    }
    if (partial) {
        float* Cp = C + (long long)blockIdx.z * partStride;
        #pragma unroll
        for (int i = 0; i < 4; ++i) {
            int m = m0 + ty * 4 + i;
            #pragma unroll
            for (int j = 0; j < 4; ++j) {
                int n = n0 + tx * 4 + j;
                if (n < N) Cp[(long long)m * N + n] = acc[i][j];
            }
        }
    } else {
        #pragma unroll
        for (int i = 0; i < 4; ++i) {
            int m = m0 + ty * 4 + i;
            #pragma unroll
            for (int j = 0; j < 4; ++j) {
                int n = n0 + tx * 4 + j;
                if (n >= N) continue;
                float v = acc[i][j] + (bias ? bias[n] : 0.0f);
                if (act == 1) v = 1.0f / (1.0f + expf(-v));
                if (dlen) v = (t < dlen[m]) ? v : 0.0f;
                C[(long long)m * ldc + coloff + n] = v;
            }
        }
    }
}

// ---------------- attention scores: e[b,p] = sum_a tanh(att1+att2)*wf + bf ----
__global__ void k_escore(const float* __restrict__ att1, const float* __restrict__ att2,
                         const float* __restrict__ wfull, const float* __restrict__ bfull,
                         float* __restrict__ e_out) {
    int gw = blockIdx.x * 4 + (threadIdx.x >> 6);   // wave per (b,p)
    int lane = threadIdx.x & 63;
    int b = gw / Pp;
    const float* a1 = att1 + (size_t)gw * Aa;
    const float* a2 = att2 + b * Aa;
    float s = 0.f;
    #pragma unroll
    for (int i = 0; i < Aa / 64; ++i) {
        int a = lane + i * 64;
        s += tanhf(a1[a] + a2[a]) * wfull[a];
    }
    #pragma unroll
    for (int o = 32; o; o >>= 1) s += __shfl_xor(s, o);
    if (lane == 0) e_out[gw] = s + bfull[0];
}

// ---------------- softmax over pixels + masked alpha output ------------------
__global__ void k_softmax(const float* __restrict__ e_in, float* __restrict__ alpha,
                          float* __restrict__ out, const int* __restrict__ dlen, int t) {
    int b = blockIdx.x;
    int tid = threadIdx.x;
    __shared__ float sh[256];
    float v = (tid < Pp) ? e_in[b * Pp + tid] : -1e30f;
    sh[tid] = v; __syncthreads();
    for (int o = 128; o; o >>= 1) { if (tid < o) sh[tid] = fmaxf(sh[tid], sh[tid + o]); __syncthreads(); }
    float mx = sh[0]; __syncthreads();
    float ex = (tid < Pp) ? expf(v - mx) : 0.0f;
    sh[tid] = ex; __syncthreads();
    for (int o = 128; o; o >>= 1) { if (tid < o) sh[tid] += sh[tid + o]; __syncthreads(); }
    float denom = sh[0];
    if (tid < Pp) {
        float al = ex / denom;
        alpha[b * Pp + tid] = al;
        out[OUT_ALPH + ((long long)b * Tt + t) * Pp + tid] = (t < dlen[b]) ? al : 0.0f;
    }
}

// ---------------- embedding slice into x[:, :512] ----------------------------
__global__ void k_xemb(const float* __restrict__ emb, const int* __restrict__ caps_s,
                       float* __restrict__ x, int t) {
    int id = blockIdx.x * 256 + threadIdx.x;   // 64*512
    int b = id >> 9, k = id & 511;
    x[b * KIH + k] = emb[(size_t)caps_s[b * Lc + t] * Ee + k];
}

// ---------------- awe = alpha . enc ; x[:,512:] = gate*awe -------------------
__global__ void k_awe(const float* __restrict__ alpha, const float* __restrict__ enc,
                      const int* __restrict__ sind, const float* __restrict__ gate,
                      float* __restrict__ x) {
    int b = blockIdx.x >> 3;
    int e = (blockIdx.x & 7) * 256 + threadIdx.x;
    __shared__ float al[Pp];
    if (threadIdx.x < Pp) al[threadIdx.x] = alpha[b * Pp + threadIdx.x];
    __syncthreads();
    const float* ep = enc + (size_t)sind[b] * Pp * ENCd + e;
    float s = 0.f;
    for (int p = 0; p < Pp; ++p) s += al[p] * ep[(size_t)p * ENCd];
    x[b * KIH + Ee + e] = gate[b * G4 + e] * s;
}

// ---------------- LSTM pointwise (sums 5 gate partials + biases) -------------
__global__ void k_lstm(const float* __restrict__ gP, const float* __restrict__ b_ih,
                       const float* __restrict__ b_hh, float* __restrict__ h,
                       float* __restrict__ c, const int* __restrict__ dlen, int t) {
    int id = blockIdx.x * 256 + threadIdx.x;   // 64*512
    int b = id >> 9, d = id & 511;
    float gi = 0, gf = 0, gg = 0, go = 0;
    #pragma unroll
    for (int s = 0; s < 5; ++s) {
        const float* g = gP + (size_t)s * Bb * G4 + (size_t)b * G4;
        gi += g[d]; gf += g[d + 512]; gg += g[d + 1024]; go += g[d + 1536];
    }
    gi += b_ih[d] + b_hh[d];
    gf += b_ih[d + 512] + b_hh[d + 512];
    gg += b_ih[d + 1024] + b_hh[d + 1024];
    go += b_ih[d + 1536] + b_hh[d + 1536];
    float ii = 1.0f / (1.0f + expf(-gi));
    float ff = 1.0f / (1.0f + expf(-gf));
    float oo = 1.0f / (1.0f + expf(-go));
    float cn = ff * c[id] + ii * tanhf(gg);
    float hn = oo * tanhf(cn);
    if (t < dlen[b]) { c[id] = cn; h[id] = hn; }
}

extern "C" void kernel_launch(void* const* d_in, const int* in_sizes, int n_in,
                              void* d_out, int out_size, void* d_ws, size_t ws_size,
                              hipStream_t stream) {
    const float* encoder_out      = (const float*)d_in[0];
    const int*   encoded_captions = (const int*)d_in[1];
    const int*   caption_lengths  = (const int*)d_in[2];
    const float* emb       = (const float*)d_in[3];
    const float* W_ih      = (const float*)d_in[4];
    const float* b_ih      = (const float*)d_in[5];
    const float* W_hh      = (const float*)d_in[6];
    const float* b_hh      = (const float*)d_in[7];
    const float* W_init_h  = (const float*)d_in[8];
    const float* b_init_h  = (const float*)d_in[9];
    const float* W_init_c  = (const float*)d_in[10];
    const float* b_init_c  = (const float*)d_in[11];
    const float* W_fbeta   = (const float*)d_in[12];
    const float* b_fbeta   = (const float*)d_in[13];
    const float* W_fc      = (const float*)d_in[14];
    const float* b_fc      = (const float*)d_in[15];
    const float* W_enc_att = (const float*)d_in[16];
    const float* b_enc_att = (const float*)d_in[17];
    const float* W_dec_att = (const float*)d_in[18];
    const float* b_dec_att = (const float*)d_in[19];
    const float* W_full_att = (const float*)d_in[20];
    const float* b_full_att = (const float*)d_in[21];
    float* out = (float*)d_out;

    char* ws = (char*)d_ws;
    int* sind   = (int*)ws;
    int* dlen   = sind + 64;
    int* caps_s = dlen + 64;           // 1280 ints
    float* fws      = (float*)(ws + 8192);
    float* mean_enc = fws;  fws += Bb * ENCd;
    float* h        = fws;  fws += Bb * Dd;
    float* c        = fws;  fws += Bb * Dd;
    float* att2     = fws;  fws += Bb * Aa;
    float* e_buf    = fws;  fws += Bb * Pp;
    float* alpha    = fws;  fws += Bb * Pp;
    float* gate     = fws;  fws += Bb * G4;
    float* x        = fws;  fws += Bb * KIH;
    float* gatesP   = fws;  fws += 5 * Bb * G4;
    float* att1     = fws;  fws += (long long)Bb * Pp * Aa;   // 25.7 MB

    k_sort<<<1, 64, 0, stream>>>(caption_lengths, encoded_captions, out, sind, dlen, caps_s);
    k_meanenc<<<512, 256, 0, stream>>>(encoder_out, sind, mean_enc);
    // h0 = mean @ W_init_h^T + b ; c0 likewise
    k_gemm<<<dim3(8, 1, 1), 256, 0, stream>>>(mean_enc, ENCd, nullptr, W_init_h, b_init_h,
          h, Dd, 0, Dd, ENCd, ENCd, 0, 0, 0, nullptr, 0);
    k_gemm<<<dim3(8, 1, 1), 256, 0, stream>>>(mean_enc, ENCd, nullptr, W_init_c, b_init_c,
          c, Dd, 0, Dd, ENCd, ENCd, 0, 0, 0, nullptr, 0);
    // att1 = enc_sorted @ W_enc_att^T + b   (12544 x 512 x 2048)
    k_gemm<<<dim3(8, 196, 1), 256, 0, stream>>>(encoder_out, ENCd, sind, W_enc_att, b_enc_att,
          att1, Aa, 0, Aa, ENCd, ENCd, 0, 0, 0, nullptr, 0);

    for (int t = 0; t < Tt; ++t) {
        // att2 = h @ W_dec_att^T + b
        k_gemm<<<dim3(8, 1, 1), 256, 0, stream>>>(h, Dd, nullptr, W_dec_att, b_dec_att,
              att2, Aa, 0, Aa, Dd, Dd, 0, 0, 0, nullptr, 0);
        // gate = sigmoid(h @ W_fbeta^T + b)
        k_gemm<<<dim3(32, 1, 1), 256, 0, stream>>>(h, Dd, nullptr, W_fbeta, b_fbeta,
              gate, G4, 0, G4, Dd, Dd, 1, 0, 0, nullptr, 0);
        k_escore<<<3136, 256, 0, stream>>>(att1, att2, W_full_att, b_full_att, e_buf);
        k_softmax<<<64, 256, 0, stream>>>(e_buf, alpha, out, dlen, t);
        k_xemb<<<128, 256, 0, stream>>>(emb, caps_s, x, t);
        k_awe<<<512, 256, 0, stream>>>(alpha, encoder_out, sind, gate, x);
        // gates partials: x @ W_ih^T  (split-K 4), h @ W_hh^T (partial idx 4)
        k_gemm<<<dim3(32, 1, 4), 256, 0, stream>>>(x, KIH, nullptr, W_ih, nullptr,
              gatesP, 0, 0, G4, KIH, KIH / 4, 0, 1, (long long)Bb * G4, nullptr, 0);
        k_gemm<<<dim3(32, 1, 1), 256, 0, stream>>>(h, Dd, nullptr, W_hh, nullptr,
              gatesP + 4ll * Bb * G4, 0, 0, G4, Dd, Dd, 0, 1, 0, nullptr, 0);
        k_lstm<<<128, 256, 0, stream>>>(gatesP, b_ih, b_hh, h, c, dlen, t);
        // preds = h_new @ W_fc^T + b_fc  -> masked write into out[b, t, :]
        k_gemm<<<dim3(157, 1, 1), 256, 0, stream>>>(h, Dd, nullptr, W_fc, b_fc,
              out + OUT_PRED, (long long)Tt * Vv, (long long)t * Vv, Vv, Dd, Dd, 0, 0, 0, dlen, t);
    }
}

// Round 2
// 2953.291 us; speedup vs baseline: 2.7807x; 2.7807x over previous
//
#include <hip/hip_runtime.h>
#include <math.h>

#define Bb 64
#define Pp 196
#define ENCd 2048
#define Lc 20
#define Tt 19
#define Vv 10000
#define Ee 512
#define Dd 512
#define Aa 512
#define K3 3072     // E + ENC + D (x3 = [emb, gate*awe, h])
#define G4 2048     // 4*D

#define OUT_PRED 0ll
#define OUT_CAPS 12160000ll   // B*T*V
#define OUT_ALPH 12161280ll   // + B*L
#define OUT_SIND 12399616ll   // + B*T*P

typedef unsigned short ushort_t;
typedef __attribute__((ext_vector_type(8))) short short8;
typedef __attribute__((ext_vector_type(4))) float f32x4;

__device__ __forceinline__ float b2f(ushort_t u) {
    union { unsigned int i; float f; } x; x.i = ((unsigned int)u) << 16; return x.f;
}
__device__ __forceinline__ ushort_t f2b(float f) {
    union { float f; unsigned int i; } x; x.f = f;
    unsigned int r = x.i + 0x7fffu + ((x.i >> 16) & 1u);
    return (ushort_t)(r >> 16);
}
__device__ __forceinline__ float fsig(float x) { return 1.0f / (1.0f + __expf(-x)); }
__device__ __forceinline__ float ftanh(float x) {
    x = fminf(fmaxf(x, -15.0f), 15.0f);
    float e = __expf(2.0f * x);
    return (e - 1.0f) / (e + 1.0f);
}

// ---------------- sort (stable descending argsort of caption lengths) --------
__global__ void k_sort(const int* __restrict__ cap_len, const int* __restrict__ caps_in,
                       float* __restrict__ out, int* __restrict__ sind,
                       int* __restrict__ dlen, int* __restrict__ caps_s) {
    __shared__ int cls[Bb];
    int i = threadIdx.x;
    int cl = cap_len[i];
    cls[i] = cl;
    __syncthreads();
    int rank = 0;
    for (int j = 0; j < Bb; ++j) {
        int cj = cls[j];
        rank += (cj > cl) || (cj == cl && j < i);
    }
    sind[rank] = i;
    dlen[rank] = cl - 1;
    out[OUT_SIND + rank] = (float)i;
    for (int l = 0; l < Lc; ++l) {
        int v = caps_in[i * Lc + l];
        caps_s[rank * Lc + l] = v;
        out[OUT_CAPS + rank * Lc + l] = (float)v;
    }
}

// ---------------- mean over pixels -> bf16 -----------------------------------
__global__ void k_meanenc(const float* __restrict__ enc, const int* __restrict__ sind,
                          ushort_t* __restrict__ mean_bf) {
    int id = blockIdx.x * 256 + threadIdx.x;   // 64*2048
    int b = id >> 11, e = id & 2047;
    const float* p = enc + (size_t)sind[b] * Pp * ENCd + e;
    float s = 0.f;
    for (int k = 0; k < Pp; ++k) s += p[(size_t)k * ENCd];
    mean_bf[id] = f2b(s * (1.0f / Pp));
}

// ---------------- fp32 -> bf16 weight convert (strided concat) ---------------
__global__ void k_cvt(const float* __restrict__ src, ushort_t* __restrict__ dst,
                      int cols, int dstStride, int dstOff, long long total4) {
    long long id = (long long)blockIdx.x * 256 + threadIdx.x;
    if (id >= total4) return;
    int c4pr = cols >> 2;
    int r = (int)(id / c4pr), c4 = (int)(id % c4pr) << 2;
    float4 v = *(const float4*)&src[(size_t)r * cols + c4];
    ushort4 o; o.x = f2b(v.x); o.y = f2b(v.y); o.z = f2b(v.z); o.w = f2b(v.w);
    *(ushort4*)&dst[(size_t)r * dstStride + dstOff + c4] = o;
}

// ---------------- bias prep --------------------------------------------------
__global__ void k_bias(const float* b_dec, const float* b_fb, const float* b_ihp,
                       const float* b_hhp, const float* b_h, const float* b_c,
                       float* b_ag, float* bsum, float* b_hc) {
    int id = blockIdx.x * 256 + threadIdx.x;   // 2560 threads
    if (id < 512) b_ag[id] = b_dec[id];
    else if (id < 2560) b_ag[id] = b_fb[id - 512];
    if (id < 2048) bsum[id] = b_ihp[id] + b_hhp[id];
    if (id < 512) b_hc[id] = b_h[id];
    else if (id < 1024) b_hc[id] = b_c[id - 512];
}

// ---------------- generic bf16 MFMA GEMM: C[M,N] = A[M,K] @ W[N,K]^T ---------
// 4 waves/block, each wave owns a 16-row m-tile, NT n-tiles of 16.
// modes: 0=att1->bf16  1=ag(sigmoid n>=512)  2=gates  3=preds(masked, out)  4=h0/c0
template<int NT, bool AF32>
__global__ void __launch_bounds__(256) k_mfma(
        const ushort_t* __restrict__ A, const float* __restrict__ Af, int lda,
        const int* __restrict__ sindp,
        const ushort_t* __restrict__ W, int K, int N,
        const float* __restrict__ bias, int mode,
        float* __restrict__ of, ushort_t* __restrict__ ob, ushort_t* __restrict__ ob2,
        long long ldc, long long coloff,
        const int* __restrict__ dlen, int t,
        const float* __restrict__ embp, const int* __restrict__ caps_s, int nbGemm) {
    if ((int)blockIdx.x >= nbGemm) {
        // fused embedding gather: x3[:, :512] = bf16(emb[caps_s[:, t]])
        int id = ((int)blockIdx.x - nbGemm) * 256 + threadIdx.x;   // 8192 = 64*128
        int b = id >> 7, k4 = (id & 127) << 2;
        float4 v = *(const float4*)&embp[(size_t)caps_s[b * Lc + t] * Ee + k4];
        ushort4 o; o.x = f2b(v.x); o.y = f2b(v.y); o.z = f2b(v.z); o.w = f2b(v.w);
        *(ushort4*)&ob2[(size_t)b * K3 + k4] = o;
        return;
    }
    int lane = threadIdx.x & 63, w = threadIdx.x >> 6;
    int m0 = blockIdx.y * 64 + w * 16;
    int n0 = blockIdx.x * (16 * NT);
    int row = m0 + (lane & 15);
    int kq = (lane >> 4) << 3;
    size_t arow;
    if (sindp) { int bb = row / Pp; arow = (size_t)(sindp[bb] * Pp + (row - bb * Pp)); }
    else arow = (size_t)row;
    const ushort_t* ap = AF32 ? nullptr : (A + arow * lda + kq);
    const float* afp = AF32 ? (Af + arow * lda + kq) : nullptr;

    f32x4 acc[NT];
    #pragma unroll
    for (int i = 0; i < NT; ++i) acc[i] = (f32x4){0.f, 0.f, 0.f, 0.f};

    for (int k0 = 0; k0 < K; k0 += 32) {
        short8 a;
        if (AF32) {
            float4 x0 = *(const float4*)(afp + k0);
            float4 x1 = *(const float4*)(afp + k0 + 4);
            a[0] = (short)f2b(x0.x); a[1] = (short)f2b(x0.y);
            a[2] = (short)f2b(x0.z); a[3] = (short)f2b(x0.w);
            a[4] = (short)f2b(x1.x); a[5] = (short)f2b(x1.y);
            a[6] = (short)f2b(x1.z); a[7] = (short)f2b(x1.w);
        } else {
            a = *(const short8*)(ap + k0);
        }
        #pragma unroll
        for (int tt2 = 0; tt2 < NT; ++tt2) {
            int n = n0 + tt2 * 16 + (lane & 15);
            short8 b8 = *(const short8*)(W + (size_t)n * K + k0 + kq);
            acc[tt2] = __builtin_amdgcn_mfma_f32_16x16x32_bf16(a, b8, acc[tt2], 0, 0, 0);
        }
    }
    #pragma unroll
    for (int tt2 = 0; tt2 < NT; ++tt2) {
        int n = n0 + tt2 * 16 + (lane & 15);
        #pragma unroll
        for (int j = 0; j < 4; ++j) {
            int m = m0 + ((lane >> 4) << 2) + j;
            float v = acc[tt2][j];
            if (bias) v += bias[n];
            if (mode == 0) {
                ob[(size_t)m * N + n] = f2b(v);
            } else if (mode == 1) {
                of[(size_t)m * N + n] = (n >= 512) ? fsig(v) : v;
            } else if (mode == 2) {
                of[(size_t)m * N + n] = v;
            } else if (mode == 3) {
                of[(size_t)m * ldc + coloff + n] = (t < dlen[m]) ? v : 0.0f;
            } else {
                if (n < 512) {
                    ushort_t hb = f2b(v);
                    ob[(size_t)m * Dd + n] = hb;
                    ob2[(size_t)m * K3 + (Ee + ENCd) + n] = hb;
                } else {
                    of[(size_t)m * Dd + (n - 512)] = v;
                }
            }
        }
    }
}

// ---------------- fused attention scores + softmax ---------------------------
// e[b,p] = sum_a tanh(att1[b,p,a] + att2[b,a]) * wf[a] + bf ; alpha=softmax_p(e)
__global__ void __launch_bounds__(256) k_esm(
        const ushort_t* __restrict__ att1, const float* __restrict__ ag,
        const float* __restrict__ wfull, const float* __restrict__ bfull,
        float* __restrict__ alpha, float* __restrict__ out,
        const int* __restrict__ dlen, int t) {
    int b = blockIdx.x;
    int lane = threadIdx.x & 63, w = threadIdx.x >> 6;
    float a2[8], wf[8];
    const float* a2p = ag + (size_t)b * 2560 + lane * 8;   // att2 = ag[:, :512]
    #pragma unroll
    for (int j = 0; j < 8; ++j) { a2[j] = a2p[j]; wf[j] = wfull[lane * 8 + j]; }
    __shared__ float e_sh[Pp];
    __shared__ float sh[256];
    for (int p = w; p < Pp; p += 4) {
        short8 a1 = *(const short8*)(att1 + ((size_t)b * Pp + p) * Aa + lane * 8);
        float s = 0.f;
        #pragma unroll
        for (int j = 0; j < 8; ++j)
            s += ftanh(b2f((ushort_t)a1[j]) + a2[j]) * wf[j];
        #pragma unroll
        for (int o = 32; o; o >>= 1) s += __shfl_xor(s, o);
        if (lane == 0) e_sh[p] = s + bfull[0];
    }
    __syncthreads();
    int tid = threadIdx.x;
    float v = (tid < Pp) ? e_sh[tid] : -1e30f;
    sh[tid] = v; __syncthreads();
    for (int o = 128; o; o >>= 1) { if (tid < o) sh[tid] = fmaxf(sh[tid], sh[tid + o]); __syncthreads(); }
    float mx = sh[0]; __syncthreads();
    float ex = (tid < Pp) ? __expf(v - mx) : 0.0f;
    sh[tid] = ex; __syncthreads();
    for (int o = 128; o; o >>= 1) { if (tid < o) sh[tid] += sh[tid + o]; __syncthreads(); }
    float denom = sh[0];
    if (tid < Pp) {
        float al = ex / denom;
        alpha[b * Pp + tid] = al;
        out[OUT_ALPH + ((long long)b * Tt + t) * Pp + tid] = (t < dlen[b]) ? al : 0.0f;
    }
}

// ---------------- awe = alpha . enc ; x3[:, 512:2560] = bf16(gate*awe) -------
__global__ void __launch_bounds__(256) k_awe(
        const float* __restrict__ alpha, const float* __restrict__ enc,
        const int* __restrict__ sind, const float* __restrict__ ag,
        ushort_t* __restrict__ x3) {
    int b = blockIdx.x >> 2, q = blockIdx.x & 3;
    int e0 = q * 512 + threadIdx.x * 2;
    __shared__ float al[Pp];
    if (threadIdx.x < Pp) al[threadIdx.x] = alpha[b * Pp + threadIdx.x];
    __syncthreads();
    const float* ep = enc + (size_t)sind[b] * Pp * ENCd + e0;
    float s0 = 0.f, s1 = 0.f;
    #pragma unroll 4
    for (int p = 0; p < Pp; ++p) {
        float2 v = *(const float2*)(ep + (size_t)p * ENCd);
        float a = al[p];
        s0 += a * v.x; s1 += a * v.y;
    }
    float g0 = ag[(size_t)b * 2560 + 512 + e0];
    float g1 = ag[(size_t)b * 2560 + 512 + e0 + 1];
    ushort2 r; r.x = f2b(g0 * s0); r.y = f2b(g1 * s1);
    *(ushort2*)&x3[(size_t)b * K3 + Ee + e0] = r;
}

// ---------------- LSTM pointwise ---------------------------------------------
__global__ void k_lstm(const float* __restrict__ gates, float* __restrict__ c,
                       ushort_t* __restrict__ h_bf, ushort_t* __restrict__ x3,
                       const int* __restrict__ dlen, int t) {
    int id = blockIdx.x * 256 + threadIdx.x;   // 64*512
    int b = id >> 9, d = id & 511;
    if (t >= dlen[b]) return;
    const float* g = gates + (size_t)b * G4;
    float gi = g[d], gf = g[d + 512], gg = g[d + 1024], go = g[d + 1536];
    float ii = fsig(gi), ff = fsig(gf), oo = fsig(go);
    float cn = ff * c[id] + ii * ftanh(gg);
    float hn = oo * ftanh(cn);
    c[id] = cn;
    ushort_t hb = f2b(hn);
    h_bf[id] = hb;
    x3[(size_t)b * K3 + (Ee + ENCd) + d] = hb;
}

extern "C" void kernel_launch(void* const* d_in, const int* in_sizes, int n_in,
                              void* d_out, int out_size, void* d_ws, size_t ws_size,
                              hipStream_t stream) {
    const float* encoder_out      = (const float*)d_in[0];
    const int*   encoded_captions = (const int*)d_in[1];
    const int*   caption_lengths  = (const int*)d_in[2];
    const float* emb       = (const float*)d_in[3];
    const float* W_ih      = (const float*)d_in[4];
    const float* b_ih      = (const float*)d_in[5];
    const float* W_hh      = (const float*)d_in[6];
    const float* b_hh      = (const float*)d_in[7];
    const float* W_init_h  = (const float*)d_in[8];
    const float* b_init_h  = (const float*)d_in[9];
    const float* W_init_c  = (const float*)d_in[10];
    const float* b_init_c  = (const float*)d_in[11];
    const float* W_fbeta   = (const float*)d_in[12];
    const float* b_fbeta   = (const float*)d_in[13];
    const float* W_fc      = (const float*)d_in[14];
    const float* b_fc      = (const float*)d_in[15];
    const float* W_enc_att = (const float*)d_in[16];
    const float* b_enc_att = (const float*)d_in[17];
    const float* W_dec_att = (const float*)d_in[18];
    const float* b_dec_att = (const float*)d_in[19];
    const float* W_full_att = (const float*)d_in[20];
    const float* b_full_att = (const float*)d_in[21];
    float* out = (float*)d_out;

    char* p = (char*)d_ws;
    auto alloc = [&](size_t bytes) { char* r = p; p += (bytes + 255) & ~255ull; return r; };
    int* sind   = (int*)alloc(64 * 4);
    int* dlen   = (int*)alloc(64 * 4);
    int* caps_s = (int*)alloc(Bb * Lc * 4);
    float* c_st  = (float*)alloc(Bb * Dd * 4);
    float* ag    = (float*)alloc(Bb * 2560 * 4);
    float* alpha = (float*)alloc(Bb * Pp * 4);
    float* gates = (float*)alloc(Bb * G4 * 4);
    float* b_ag  = (float*)alloc(2560 * 4);
    float* bsum  = (float*)alloc(2048 * 4);
    float* b_hc  = (float*)alloc(1024 * 4);
    ushort_t* mean_bf = (ushort_t*)alloc((size_t)Bb * ENCd * 2);
    ushort_t* h_bf    = (ushort_t*)alloc((size_t)Bb * Dd * 2);
    ushort_t* x3      = (ushort_t*)alloc((size_t)Bb * K3 * 2);
    ushort_t* att1    = (ushort_t*)alloc((size_t)Bb * Pp * Aa * 2);    // 12.85 MB
    ushort_t* W_enc   = (ushort_t*)alloc((size_t)Aa * ENCd * 2);       // 2 MB
    ushort_t* W_ag    = (ushort_t*)alloc((size_t)2560 * Dd * 2);       // 2.6 MB
    ushort_t* W_cat   = (ushort_t*)alloc((size_t)G4 * K3 * 2);         // 12.6 MB
    ushort_t* W_fcb   = (ushort_t*)alloc((size_t)Vv * Dd * 2);         // 10.2 MB
    ushort_t* W_hcb   = (ushort_t*)alloc((size_t)1024 * ENCd * 2);     // 4.2 MB

    k_sort<<<1, 64, 0, stream>>>(caption_lengths, encoded_captions, out, sind, dlen, caps_s);
    k_meanenc<<<512, 256, 0, stream>>>(encoder_out, sind, mean_bf);
    k_bias<<<10, 256, 0, stream>>>(b_dec_att, b_fbeta, b_ih, b_hh, b_init_h, b_init_c,
                                   b_ag, bsum, b_hc);
    // weight conversions
    k_cvt<<<256, 256, 0, stream>>>(W_dec_att, W_ag, 512, 512, 0, 512ll * 128);
    k_cvt<<<1024, 256, 0, stream>>>(W_fbeta, W_ag + 512 * 512, 512, 512, 0, 2048ll * 128);
    k_cvt<<<5120, 256, 0, stream>>>(W_ih, W_cat, 2560, K3, 0, 2048ll * 640);
    k_cvt<<<1024, 256, 0, stream>>>(W_hh, W_cat, 512, K3, 2560, 2048ll * 128);
    k_cvt<<<5000, 256, 0, stream>>>(W_fc, W_fcb, 512, 512, 0, 10000ll * 128);
    k_cvt<<<1024, 256, 0, stream>>>(W_enc_att, W_enc, 2048, 2048, 0, 512ll * 512);
    k_cvt<<<1024, 256, 0, stream>>>(W_init_h, W_hcb, 2048, 2048, 0, 512ll * 512);
    k_cvt<<<1024, 256, 0, stream>>>(W_init_c, W_hcb + 512 * 2048, 2048, 2048, 0, 512ll * 512);
    // h0/c0: mean_bf @ W_hcb^T -> h_bf, x3 h-part, c  (N=1024, 16 blocks)
    k_mfma<4, false><<<dim3(16, 1), 256, 0, stream>>>(
        mean_bf, nullptr, ENCd, nullptr, W_hcb, ENCd, 1024, b_hc, 4,
        c_st, h_bf, x3, 0, 0, nullptr, 0, nullptr, nullptr, 16);
    // att1 = enc_sorted @ W_enc^T -> bf16  (M=12544, N=512, K=2048)
    k_mfma<8, true><<<dim3(4, 196), 256, 0, stream>>>(
        nullptr, encoder_out, ENCd, sind, W_enc, ENCd, Aa, b_enc_att, 0,
        nullptr, att1, nullptr, 0, 0, nullptr, 0, nullptr, nullptr, 4);

    for (int t = 0; t < Tt; ++t) {
        // ag = h @ [W_dec_att;W_fbeta]^T (+sigmoid on gate part); +32 emb-gather blocks
        k_mfma<4, false><<<dim3(42, 1), 256, 0, stream>>>(
            h_bf, nullptr, Dd, nullptr, W_ag, Dd, 2560, b_ag, 1,
            ag, nullptr, x3, 0, 0, nullptr, t, emb, caps_s, 10);
        k_esm<<<64, 256, 0, stream>>>(att1, ag, W_full_att, b_full_att, alpha, out, dlen, t);
        k_awe<<<256, 256, 0, stream>>>(alpha, encoder_out, sind, ag, x3);
        // gates = x3 @ [W_ih|W_hh]^T + (b_ih+b_hh)   (N=2048, K=3072)
        k_mfma<2, false><<<dim3(64, 1), 256, 0, stream>>>(
            x3, nullptr, K3, nullptr, W_cat, K3, G4, bsum, 2,
            gates, nullptr, nullptr, 0, 0, nullptr, 0, nullptr, nullptr, 64);
        k_lstm<<<128, 256, 0, stream>>>(gates, c_st, h_bf, x3, dlen, t);
        // preds = h @ W_fc^T + b_fc -> out (masked)   (N=10000, NT=5 -> 125 blocks)
        k_mfma<5, false><<<dim3(125, 1), 256, 0, stream>>>(
            h_bf, nullptr, Dd, nullptr, W_fcb, Dd, Vv, b_fc, 3,
            out + OUT_PRED, nullptr, nullptr, (long long)Tt * Vv, (long long)t * Vv,
            dlen, t, nullptr, nullptr, 125);
    }
}

// Round 3
// 1744.194 us; speedup vs baseline: 4.7082x; 1.6932x over previous
//
#include <hip/hip_runtime.h>
#include <math.h>

#define Bb 64
#define Pp 196
#define ENCd 2048
#define Lc 20
#define Tt 19
#define Vv 10000
#define Ee 512
#define Dd 512
#define Aa 512
#define K2 2560     // E + ENC  (x2 = [emb, gate*awe])
#define KG 3072     // E + ENC + D
#define G4 2048     // 4*D

#define OUT_PRED 0ll
#define OUT_CAPS 12160000ll   // B*T*V
#define OUT_ALPH 12161280ll   // + B*L
#define OUT_SIND 12399616ll   // + B*T*P

typedef unsigned short ushort_t;
typedef __attribute__((ext_vector_type(8))) short short8;
typedef __attribute__((ext_vector_type(4))) float f32x4;

__device__ __forceinline__ float b2f(ushort_t u) {
    union { unsigned int i; float f; } x; x.i = ((unsigned int)u) << 16; return x.f;
}
__device__ __forceinline__ ushort_t f2b(float f) {
    union { float f; unsigned int i; } x; x.f = f;
    unsigned int r = x.i + 0x7fffu + ((x.i >> 16) & 1u);
    return (ushort_t)(r >> 16);
}
__device__ __forceinline__ float fsig(float x) { return 1.0f / (1.0f + __expf(-x)); }
__device__ __forceinline__ float ftanh(float x) {
    x = fminf(fmaxf(x, -15.0f), 15.0f);
    float e = __expf(2.0f * x);
    return (e - 1.0f) / (e + 1.0f);
}

// ---------------- sort (stable descending argsort of caption lengths) --------
__global__ void k_sort(const int* __restrict__ cap_len, const int* __restrict__ caps_in,
                       float* __restrict__ out, int* __restrict__ sind,
                       int* __restrict__ dlen, int* __restrict__ caps_s) {
    __shared__ int cls[Bb];
    int i = threadIdx.x;
    int cl = cap_len[i];
    cls[i] = cl;
    __syncthreads();
    int rank = 0;
    for (int j = 0; j < Bb; ++j) {
        int cj = cls[j];
        rank += (cj > cl) || (cj == cl && j < i);
    }
    sind[rank] = i;
    dlen[rank] = cl - 1;
    out[OUT_SIND + rank] = (float)i;
    for (int l = 0; l < Lc; ++l) {
        int v = caps_in[i * Lc + l];
        caps_s[rank * Lc + l] = v;
        out[OUT_CAPS + rank * Lc + l] = (float)v;
    }
}

// ---------------- merged weight conversions ----------------------------------
__device__ __forceinline__ void cvtseg(const float* __restrict__ src, ushort_t* __restrict__ dst,
                                       int cols, int stride, int off, int bid0, long long quads) {
    long long qid = (long long)bid0 * 256 + threadIdx.x;
    if (qid >= quads) return;
    int c4pr = cols >> 2;
    int r = (int)(qid / c4pr), c4 = (int)(qid % c4pr) << 2;
    float4 v = *(const float4*)&src[(size_t)r * cols + c4];
    ushort4 o; o.x = f2b(v.x); o.y = f2b(v.y); o.z = f2b(v.z); o.w = f2b(v.w);
    *(ushort4*)&dst[(size_t)r * stride + off + c4] = o;
}

__global__ void k_cvtall(const float* Wdec, const float* Wfb, const float* Wih,
                         const float* Whh, const float* Wfc, const float* Wenc_f,
                         const float* Wih0, const float* Wic0,
                         ushort_t* W_ag, ushort_t* W_cat, ushort_t* W_fcb,
                         ushort_t* W_enc, ushort_t* W_hcb) {
    int b = blockIdx.x;
    if      (b < 256)   cvtseg(Wdec,  W_ag,               512,  512,  0,    b,         65536);
    else if (b < 1280)  cvtseg(Wfb,   W_ag + 512 * 512,   512,  512,  0,    b - 256,   262144);
    else if (b < 6400)  cvtseg(Wih,   W_cat,              2560, 3072, 0,    b - 1280,  1310720);
    else if (b < 7424)  cvtseg(Whh,   W_cat,              512,  3072, 2560, b - 6400,  262144);
    else if (b < 12424) cvtseg(Wfc,   W_fcb,              512,  512,  0,    b - 7424,  1280000);
    else if (b < 13448) cvtseg(Wenc_f,W_enc,              2048, 2048, 0,    b - 12424, 262144);
    else if (b < 14472) cvtseg(Wih0,  W_hcb,              2048, 2048, 0,    b - 13448, 262144);
    else                cvtseg(Wic0,  W_hcb + 512 * 2048, 2048, 2048, 0,    b - 14472, 262144);
}

// ---------------- bias prep --------------------------------------------------
__global__ void k_bias(const float* b_dec, const float* b_fb, const float* b_ihp,
                       const float* b_hhp, const float* b_h, const float* b_c,
                       float* b_ag, float* bsum, float* b_hc) {
    int id = blockIdx.x * 256 + threadIdx.x;
    if (id < 512) b_ag[id] = b_dec[id];
    else if (id < 2560) b_ag[id] = b_fb[id - 512];
    if (id < 2048) bsum[id] = b_ihp[id] + b_hhp[id];
    if (id < 512) b_hc[id] = b_h[id];
    else if (id < 1024) b_hc[id] = b_c[id - 512];
}

// ---------------- gather+convert encoder_out (sorted) -> bf16 ----------------
__global__ void __launch_bounds__(256) k_enccvt(const float* __restrict__ enc,
                                                const int* __restrict__ sind,
                                                ushort_t* __restrict__ enc_bf) {
    int r = blockIdx.x;                 // 12544 rows
    int b = r / Pp;
    size_t srow = (size_t)sind[b] * Pp + (r - b * Pp);
    int e8 = threadIdx.x * 8;
    const float* s = enc + srow * ENCd + e8;
    float4 v0 = *(const float4*)s;
    float4 v1 = *(const float4*)(s + 4);
    short8 o;
    o[0] = (short)f2b(v0.x); o[1] = (short)f2b(v0.y); o[2] = (short)f2b(v0.z); o[3] = (short)f2b(v0.w);
    o[4] = (short)f2b(v1.x); o[5] = (short)f2b(v1.y); o[6] = (short)f2b(v1.z); o[7] = (short)f2b(v1.w);
    *(short8*)&enc_bf[(size_t)r * ENCd + e8] = o;
}

// ---------------- mean over pixels (from bf16) -------------------------------
__global__ void __launch_bounds__(1024) k_meanenc(const ushort_t* __restrict__ enc_bf,
                                                  ushort_t* __restrict__ mean_bf) {
    int b = blockIdx.x;
    int lane = threadIdx.x & 63, w = threadIdx.x >> 6;
    int cg = w & 3, pg = w >> 2;                      // 4 col-groups, 4 p-groups
    int lc = cg * 512 + lane * 8;
    __shared__ float red[4][2048];
    float acc[8] = {};
    for (int p = pg; p < Pp; p += 4) {
        short8 v = *(const short8*)&enc_bf[((size_t)b * Pp + p) * ENCd + lc];
        #pragma unroll
        for (int j = 0; j < 8; ++j) acc[j] += b2f((ushort_t)v[j]);
    }
    #pragma unroll
    for (int j = 0; j < 8; ++j) red[pg][lc + j] = acc[j];
    __syncthreads();
    int tid = threadIdx.x;
    float2 s = {0.f, 0.f};
    #pragma unroll
    for (int g = 0; g < 4; ++g) {
        float2 v = *(const float2*)&red[g][tid * 2];
        s.x += v.x; s.y += v.y;
    }
    ushort2 o; o.x = f2b(s.x * (1.0f / Pp)); o.y = f2b(s.y * (1.0f / Pp));
    *(ushort2*)&mean_bf[(size_t)b * ENCd + tid * 2] = o;
}

// ---------------- att1 = enc_bf @ W_enc^T + b -> bf16 ------------------------
__global__ void __launch_bounds__(256) k_att1(const ushort_t* __restrict__ enc_bf,
                                              const ushort_t* __restrict__ Wenc,
                                              const float* __restrict__ benc,
                                              ushort_t* __restrict__ att1) {
    int lane = threadIdx.x & 63, w = threadIdx.x >> 6;
    int r16 = lane & 15, kq = (lane >> 4) << 3;
    int mbase = blockIdx.y * 128 + w * 32;
    int n0 = blockIdx.x * 128;
    f32x4 acc[2][8];
    #pragma unroll
    for (int i = 0; i < 2; ++i)
        #pragma unroll
        for (int j = 0; j < 8; ++j) acc[i][j] = (f32x4){0.f, 0.f, 0.f, 0.f};
    for (int k0 = 0; k0 < ENCd; k0 += 32) {
        short8 a0 = *(const short8*)&enc_bf[(size_t)(mbase + r16) * ENCd + k0 + kq];
        short8 a1 = *(const short8*)&enc_bf[(size_t)(mbase + 16 + r16) * ENCd + k0 + kq];
        #pragma unroll
        for (int tt = 0; tt < 8; ++tt) {
            short8 bw = *(const short8*)&Wenc[(size_t)(n0 + tt * 16 + r16) * ENCd + k0 + kq];
            acc[0][tt] = __builtin_amdgcn_mfma_f32_16x16x32_bf16(a0, bw, acc[0][tt], 0, 0, 0);
            acc[1][tt] = __builtin_amdgcn_mfma_f32_16x16x32_bf16(a1, bw, acc[1][tt], 0, 0, 0);
        }
    }
    #pragma unroll
    for (int mf = 0; mf < 2; ++mf)
        #pragma unroll
        for (int tt = 0; tt < 8; ++tt)
            #pragma unroll
            for (int j = 0; j < 4; ++j) {
                int row = mbase + mf * 16 + ((lane >> 4) << 2) + j;
                int col = n0 + tt * 16 + r16;
                att1[(size_t)row * Aa + col] = f2b(acc[mf][tt][j] + benc[col]);
            }
}

// ---------------- unified small GEMM, split-K over 4 waves -------------------
// M=64. MODE: 0=AG (att2|sigmoid gate), 1=GATES+LSTM, 2=PREDS(masked->out), 3=H0C0
template<int NT, int MODE>
__global__ void __launch_bounds__(256) k_sgemm(
        const ushort_t* __restrict__ A, int lda,
        const ushort_t* __restrict__ W, int ldw, int K, int nblock, int nstride,
        const float* __restrict__ bias,
        float* __restrict__ of, ushort_t* __restrict__ hin, ushort_t* __restrict__ hout,
        ushort_t* __restrict__ x2, float* __restrict__ cst,
        long long ldc, long long coloff,
        const int* __restrict__ dlen, int t) {
    int lane = threadIdx.x & 63, w = threadIdx.x >> 6;
    int r16 = lane & 15, kq = (lane >> 4) << 3;
    int ncol[NT];
    #pragma unroll
    for (int tt = 0; tt < NT; ++tt) ncol[tt] = blockIdx.x * nblock + tt * nstride + r16;
    f32x4 acc[4][NT];
    #pragma unroll
    for (int mt = 0; mt < 4; ++mt)
        #pragma unroll
        for (int tt = 0; tt < NT; ++tt) acc[mt][tt] = (f32x4){0.f, 0.f, 0.f, 0.f};
    int kper = K >> 2;
    for (int k0 = w * kper; k0 < w * kper + kper; k0 += 32) {
        short8 a[4];
        #pragma unroll
        for (int mt = 0; mt < 4; ++mt) {
            const ushort_t* s;
            if (MODE == 1 && k0 >= K2) s = hin + (size_t)(mt * 16 + r16) * Dd + (k0 - K2) + kq;
            else                       s = A   + (size_t)(mt * 16 + r16) * lda + k0 + kq;
            a[mt] = *(const short8*)s;
        }
        #pragma unroll
        for (int tt = 0; tt < NT; ++tt) {
            short8 bw = *(const short8*)&W[(size_t)ncol[tt] * ldw + k0 + kq];
            #pragma unroll
            for (int mt = 0; mt < 4; ++mt)
                acc[mt][tt] = __builtin_amdgcn_mfma_f32_16x16x32_bf16(a[mt], bw, acc[mt][tt], 0, 0, 0);
        }
    }
    // split-K reduce across waves
    __shared__ float red[2][64][NT * 16 + 4];
    if (w >= 2) {
        float* row = &red[w - 2][lane][0];
        #pragma unroll
        for (int mt = 0; mt < 4; ++mt)
            #pragma unroll
            for (int tt = 0; tt < NT; ++tt) *(f32x4*)&row[(mt * NT + tt) * 4] = acc[mt][tt];
    }
    __syncthreads();
    if (w < 2) {
        float* row = &red[w][lane][0];
        #pragma unroll
        for (int mt = 0; mt < 4; ++mt)
            #pragma unroll
            for (int tt = 0; tt < NT; ++tt) acc[mt][tt] += *(f32x4*)&row[(mt * NT + tt) * 4];
    }
    __syncthreads();
    if (w == 1) {
        float* row = &red[0][lane][0];
        #pragma unroll
        for (int mt = 0; mt < 4; ++mt)
            #pragma unroll
            for (int tt = 0; tt < NT; ++tt) *(f32x4*)&row[(mt * NT + tt) * 4] = acc[mt][tt];
    }
    __syncthreads();
    if (w != 0) return;
    {
        float* row = &red[0][lane][0];
        #pragma unroll
        for (int mt = 0; mt < 4; ++mt)
            #pragma unroll
            for (int tt = 0; tt < NT; ++tt) acc[mt][tt] += *(f32x4*)&row[(mt * NT + tt) * 4];
    }
    // epilogue (wave 0 only)
    if (MODE == 0) {
        int col = ncol[0];
        float bv = bias[col];
        #pragma unroll
        for (int mt = 0; mt < 4; ++mt)
            #pragma unroll
            for (int j = 0; j < 4; ++j) {
                int row = mt * 16 + ((lane >> 4) << 2) + j;
                float v = acc[mt][0][j] + bv;
                of[(size_t)row * K2 + col] = (col >= 512) ? fsig(v) : v;
            }
    } else if (MODE == 1) {
        int d = ncol[0];
        float bi = bias[d], bf_ = bias[d + 512], bg = bias[d + 1024], bo = bias[d + 1536];
        #pragma unroll
        for (int mt = 0; mt < 4; ++mt)
            #pragma unroll
            for (int j = 0; j < 4; ++j) {
                int row = mt * 16 + ((lane >> 4) << 2) + j;
                ushort_t hb;
                if (t < dlen[row]) {
                    float gi = acc[mt][0][j] + bi, gf = acc[mt][1][j] + bf_;
                    float gg = acc[mt][2][j] + bg, go = acc[mt][3][j] + bo;
                    float cv = cst[row * Dd + d];
                    float cn = fsig(gf) * cv + fsig(gi) * ftanh(gg);
                    float hn = fsig(go) * ftanh(cn);
                    cst[row * Dd + d] = cn;
                    hb = f2b(hn);
                } else {
                    hb = hin[row * Dd + d];
                }
                hout[row * Dd + d] = hb;
            }
    } else if (MODE == 2) {
        #pragma unroll
        for (int mt = 0; mt < 4; ++mt)
            #pragma unroll
            for (int tt = 0; tt < NT; ++tt) {
                int col = ncol[tt];
                float bv = bias[col];
                #pragma unroll
                for (int j = 0; j < 4; ++j) {
                    int row = mt * 16 + ((lane >> 4) << 2) + j;
                    of[(long long)row * ldc + coloff + col] = (t < dlen[row]) ? acc[mt][tt][j] + bv : 0.0f;
                }
            }
    } else {  // MODE 3: h0 / c0
        #pragma unroll
        for (int mt = 0; mt < 4; ++mt)
            #pragma unroll
            for (int tt = 0; tt < NT; ++tt) {
                int col = ncol[tt];
                float bv = bias[col];
                #pragma unroll
                for (int j = 0; j < 4; ++j) {
                    int row = mt * 16 + ((lane >> 4) << 2) + j;
                    float v = acc[mt][tt][j] + bv;
                    if (col < 512) hout[row * Dd + col] = f2b(v);
                    else           cst[row * Dd + (col - 512)] = v;
                }
            }
    }
}

// ---------------- fused e-score + softmax ------------------------------------
__global__ void __launch_bounds__(1024) k_esm(
        const ushort_t* __restrict__ att1, const float* __restrict__ ag,
        const float* __restrict__ wfull, const float* __restrict__ bfull,
        float* __restrict__ alpha, float* __restrict__ out,
        const int* __restrict__ dlen, int t) {
    int b = blockIdx.x;
    int lane = threadIdx.x & 63, w = threadIdx.x >> 6;
    int tid = threadIdx.x;
    float a2[8], wf[8];
    {
        const float* a2p = ag + (size_t)b * K2 + lane * 8;
        float4 x0 = *(const float4*)a2p, x1 = *(const float4*)(a2p + 4);
        a2[0] = x0.x; a2[1] = x0.y; a2[2] = x0.z; a2[3] = x0.w;
        a2[4] = x1.x; a2[5] = x1.y; a2[6] = x1.z; a2[7] = x1.w;
        const float* wp = wfull + lane * 8;
        float4 y0 = *(const float4*)wp, y1 = *(const float4*)(wp + 4);
        wf[0] = y0.x; wf[1] = y0.y; wf[2] = y0.z; wf[3] = y0.w;
        wf[4] = y1.x; wf[5] = y1.y; wf[6] = y1.z; wf[7] = y1.w;
    }
    __shared__ float e_sh[Pp];
    __shared__ float sh[256];
    for (int p = w; p < Pp; p += 16) {
        short8 a1 = *(const short8*)&att1[((size_t)b * Pp + p) * Aa + lane * 8];
        float s = 0.f;
        #pragma unroll
        for (int j = 0; j < 8; ++j)
            s += ftanh(b2f((ushort_t)a1[j]) + a2[j]) * wf[j];
        #pragma unroll
        for (int o = 32; o; o >>= 1) s += __shfl_xor(s, o);
        if (lane == 0) e_sh[p] = s + bfull[0];
    }
    __syncthreads();
    float v = (tid < Pp) ? e_sh[tid] : -1e30f;
    if (tid < 256) sh[tid] = v;
    __syncthreads();
    for (int o = 128; o; o >>= 1) { if (tid < o) sh[tid] = fmaxf(sh[tid], sh[tid + o]); __syncthreads(); }
    float mx = sh[0]; __syncthreads();
    float ex = (tid < Pp) ? __expf(v - mx) : 0.0f;
    if (tid < 256) sh[tid] = ex;
    __syncthreads();
    for (int o = 128; o; o >>= 1) { if (tid < o) sh[tid] += sh[tid + o]; __syncthreads(); }
    float denom = sh[0];
    if (tid < Pp) {
        float al = ex / denom;
        alpha[b * Pp + tid] = al;
        out[OUT_ALPH + ((long long)b * Tt + t) * Pp + tid] = (t < dlen[b]) ? al : 0.0f;
    }
}

// ---------------- awe = alpha.enc ; x2[:,512:] = bf16(gate*awe); + emb gather
__global__ void __launch_bounds__(1024) k_awe(
        const float* __restrict__ alpha, const ushort_t* __restrict__ enc_bf,
        const float* __restrict__ ag, ushort_t* __restrict__ x2,
        const float* __restrict__ emb, const int* __restrict__ caps_s, int t) {
    if ((int)blockIdx.x >= 128) {
        int gid = ((int)blockIdx.x - 128) * 1024 + threadIdx.x;   // 16384 = 64*256
        int b = gid >> 8, k2 = (gid & 255) * 2;
        float2 e = *(const float2*)&emb[(size_t)caps_s[b * Lc + t] * Ee + k2];
        ushort2 o; o.x = f2b(e.x); o.y = f2b(e.y);
        *(ushort2*)&x2[(size_t)b * K2 + k2] = o;
        return;
    }
    int b = blockIdx.x >> 1, half = blockIdx.x & 1;
    int lane = threadIdx.x & 63, w = threadIdx.x >> 6;
    int cg = w & 1, pg = w >> 1;                     // 2 col-groups, 8 p-groups
    int lc = cg * 512 + lane * 8;
    __shared__ float al[Pp];
    __shared__ float red[8][1024];
    if (threadIdx.x < Pp) al[threadIdx.x] = alpha[b * Pp + threadIdx.x];
    __syncthreads();
    float acc[8] = {};
    const ushort_t* ep = enc_bf + ((size_t)b * Pp) * ENCd + half * 1024 + lc;
    for (int p = pg; p < Pp; p += 8) {
        float a = al[p];
        short8 v = *(const short8*)(ep + (size_t)p * ENCd);
        #pragma unroll
        for (int j = 0; j < 8; ++j) acc[j] += a * b2f((ushort_t)v[j]);
    }
    *(f32x4*)&red[pg][lc] = *(f32x4*)&acc[0];
    *(f32x4*)&red[pg][lc + 4] = *(f32x4*)&acc[4];
    __syncthreads();
    int tid = threadIdx.x;
    float s = 0.f;
    #pragma unroll
    for (int g = 0; g < 8; ++g) s += red[g][tid];
    int col = half * 1024 + tid;
    float gte = ag[(size_t)b * K2 + 512 + col];
    x2[(size_t)b * K2 + 512 + col] = f2b(gte * s);
}

extern "C" void kernel_launch(void* const* d_in, const int* in_sizes, int n_in,
                              void* d_out, int out_size, void* d_ws, size_t ws_size,
                              hipStream_t stream) {
    const float* encoder_out      = (const float*)d_in[0];
    const int*   encoded_captions = (const int*)d_in[1];
    const int*   caption_lengths  = (const int*)d_in[2];
    const float* emb       = (const float*)d_in[3];
    const float* W_ih      = (const float*)d_in[4];
    const float* b_ih      = (const float*)d_in[5];
    const float* W_hh      = (const float*)d_in[6];
    const float* b_hh      = (const float*)d_in[7];
    const float* W_init_h  = (const float*)d_in[8];
    const float* b_init_h  = (const float*)d_in[9];
    const float* W_init_c  = (const float*)d_in[10];
    const float* b_init_c  = (const float*)d_in[11];
    const float* W_fbeta   = (const float*)d_in[12];
    const float* b_fbeta   = (const float*)d_in[13];
    const float* W_fc      = (const float*)d_in[14];
    const float* b_fc      = (const float*)d_in[15];
    const float* W_enc_att = (const float*)d_in[16];
    const float* b_enc_att = (const float*)d_in[17];
    const float* W_dec_att = (const float*)d_in[18];
    const float* b_dec_att = (const float*)d_in[19];
    const float* W_full_att = (const float*)d_in[20];
    const float* b_full_att = (const float*)d_in[21];
    float* out = (float*)d_out;

    char* p = (char*)d_ws;
    auto alloc = [&](size_t bytes) { char* r = p; p += (bytes + 255) & ~255ull; return r; };
    int* sind   = (int*)alloc(64 * 4);
    int* dlen   = (int*)alloc(64 * 4);
    int* caps_s = (int*)alloc(Bb * Lc * 4);
    float* c_st  = (float*)alloc(Bb * Dd * 4);
    float* ag    = (float*)alloc((size_t)Bb * K2 * 4);
    float* alpha = (float*)alloc(Bb * Pp * 4);
    float* b_ag  = (float*)alloc(K2 * 4);
    float* bsum  = (float*)alloc(G4 * 4);
    float* b_hc  = (float*)alloc(1024 * 4);
    ushort_t* mean_bf = (ushort_t*)alloc((size_t)Bb * ENCd * 2);
    ushort_t* hb0     = (ushort_t*)alloc((size_t)Bb * Dd * 2);
    ushort_t* hb1     = (ushort_t*)alloc((size_t)Bb * Dd * 2);
    ushort_t* x2      = (ushort_t*)alloc((size_t)Bb * K2 * 2);
    ushort_t* att1    = (ushort_t*)alloc((size_t)Bb * Pp * Aa * 2);      // 12.85 MB
    ushort_t* W_enc   = (ushort_t*)alloc((size_t)Aa * ENCd * 2);         // 2 MB
    ushort_t* W_ag    = (ushort_t*)alloc((size_t)K2 * Dd * 2);           // 2.6 MB
    ushort_t* W_cat   = (ushort_t*)alloc((size_t)G4 * KG * 2);           // 12.6 MB
    ushort_t* W_fcb   = (ushort_t*)alloc((size_t)Vv * Dd * 2);           // 10.2 MB
    ushort_t* W_hcb   = (ushort_t*)alloc((size_t)1024 * ENCd * 2);       // 4.2 MB
    ushort_t* enc_bf  = (ushort_t*)alloc((size_t)Bb * Pp * ENCd * 2);    // 51.4 MB

    ushort_t* hb[2] = {hb0, hb1};

    k_sort<<<1, 64, 0, stream>>>(caption_lengths, encoded_captions, out, sind, dlen, caps_s);
    k_cvtall<<<15496, 256, 0, stream>>>(W_dec_att, W_fbeta, W_ih, W_hh, W_fc, W_enc_att,
                                        W_init_h, W_init_c, W_ag, W_cat, W_fcb, W_enc, W_hcb);
    k_bias<<<10, 256, 0, stream>>>(b_dec_att, b_fbeta, b_ih, b_hh, b_init_h, b_init_c,
                                   b_ag, bsum, b_hc);
    k_enccvt<<<12544, 256, 0, stream>>>(encoder_out, sind, enc_bf);
    k_meanenc<<<64, 1024, 0, stream>>>(enc_bf, mean_bf);
    // h0/c0
    k_sgemm<4, 3><<<16, 256, 0, stream>>>(mean_bf, ENCd, W_hcb, ENCd, ENCd, 64, 16,
        b_hc, nullptr, nullptr, hb0, nullptr, c_st, 0, 0, nullptr, 0);
    // att1
    k_att1<<<dim3(4, 98), 256, 0, stream>>>(enc_bf, W_enc, b_enc_att, att1);

    for (int t = 0; t < Tt; ++t) {
        ushort_t* hcur = hb[t & 1];
        ushort_t* hnext = hb[(t + 1) & 1];
        // ag = h @ [W_dec;W_fbeta]^T  (att2 raw | sigmoid gate)
        k_sgemm<1, 0><<<160, 256, 0, stream>>>(hcur, Dd, W_ag, Dd, Dd, 16, 16,
            b_ag, ag, nullptr, nullptr, nullptr, nullptr, 0, 0, nullptr, 0);
        k_esm<<<64, 1024, 0, stream>>>(att1, ag, W_full_att, b_full_att, alpha, out, dlen, t);
        k_awe<<<144, 1024, 0, stream>>>(alpha, enc_bf, ag, x2, emb, caps_s, t);
        // gates + LSTM fused; h ping-pong
        k_sgemm<4, 1><<<32, 256, 0, stream>>>(x2, K2, W_cat, KG, KG, 16, 512,
            bsum, nullptr, hcur, hnext, x2, c_st, 0, 0, dlen, t);
        // preds
        k_sgemm<5, 2><<<125, 256, 0, stream>>>(hnext, Dd, W_fcb, Dd, Dd, 80, 16,
            b_fc, out + OUT_PRED, nullptr, nullptr, nullptr, nullptr,
            (long long)Tt * Vv, (long long)t * Vv, dlen, t);
    }
}